// Round 7
// baseline (501.933 us; speedup 1.0000x reference)
//
#include <hip/hip_runtime.h>
#include <math.h>

namespace {
constexpr int Vv  = 50257;
constexpr int Dc  = 128;
constexpr int Kc  = 3;
constexpr int NBc = 8;
constexpr int Jc  = 24;      // K*NB
constexpr int Tc  = 64;
constexpr int CHV = 1024;                      // vocab elems per block chunk
constexpr int NCH = (Vv + CHV - 1) / CHV;      // 50
constexpr float INV_SQRT_D = 0.08838834764831845f;
constexpr float DIVW = 2.0f;

// ws layout (float offsets)
constexpr size_t WS_PSI  = 0;        // 24*128
constexpr size_t WS_G    = 4096;     // 24*24 (psi gram)
constexpr size_t WS_BB   = 5120;     // 24*24 (raw bubble gram)
constexpr size_t WS_XN   = 6144;     // 64   |x_t|^2
constexpr size_t WS_BX   = 6400;     // 64*24 bub_j . x_t
constexpr size_t WS_WALL = 8192;     // 64*24
constexpr size_t WS_PART = 12288;    // 64*50*9 = 28800
constexpr size_t WS_LOGZ = 45056;    // 64*4
constexpr size_t WS_P2T  = 65536;    // V*24, layout [v][j]: row = 96B, 16B-aligned

// out layout (float offsets), reference return order
constexpr size_t OFF_TOK = 0;
constexpr size_t OFF_RHO = (size_t)Tc * Vv;
constexpr size_t OFF_S   = OFF_RHO + (size_t)Tc * Dc * Dc;
constexpr size_t OFF_H   = OFF_S + Tc;
constexpr size_t OFF_F   = OFF_H + Tc;
constexpr size_t OFF_PF  = OFF_F + Tc;
}

__device__ __forceinline__ float wsum64(float v) {
#pragma unroll
  for (int m = 1; m < 64; m <<= 1) v += __shfl_xor(v, m);
  return v;
}

// online-softmax merge helpers
__device__ __forceinline__ void comb(float& m1, float& s1, float m2, float s2) {
  float M = fmaxf(m1, m2);
  float e1 = (s1 > 0.f) ? expf(m1 - M) : 0.f;
  float e2 = (s2 > 0.f) ? expf(m2 - M) : 0.f;
  s1 = s1 * e1 + s2 * e2;
  m1 = M;
}
__device__ __forceinline__ void comb_sl(float& m1, float& s1, float& sl1,
                                        float m2, float s2, float sl2) {
  float M = fmaxf(m1, m2);
  float e1 = (s1 > 0.f) ? expf(m1 - M) : 0.f;
  float e2 = (s2 > 0.f) ? expf(m2 - M) : 0.f;
  s1 = s1 * e1 + s2 * e2;
  sl1 = sl1 * e1 + sl2 * e2;
  m1 = M;
}

// shared logit recompute: 6 float4 loads + sequential FMA chains (identical
// op order in pass1 and pass2 so both passes produce identical l-values)
__device__ __forceinline__ void logits_from_row(const float* __restrict__ p2,
                                                const float* __restrict__ wsh,
                                                int v, float& l0, float& l1, float& l2) {
  const float4* row = (const float4*)(p2 + (size_t)v * Jc);
  float4 q0 = row[0], q1 = row[1], q2 = row[2], q3 = row[3], q4 = row[4], q5 = row[5];
  l0 = 0.f; l1 = 0.f; l2 = 0.f;
  l0 += wsh[0]  * q0.x; l0 += wsh[1]  * q0.y; l0 += wsh[2]  * q0.z; l0 += wsh[3]  * q0.w;
  l0 += wsh[4]  * q1.x; l0 += wsh[5]  * q1.y; l0 += wsh[6]  * q1.z; l0 += wsh[7]  * q1.w;
  l1 += wsh[8]  * q2.x; l1 += wsh[9]  * q2.y; l1 += wsh[10] * q2.z; l1 += wsh[11] * q2.w;
  l1 += wsh[12] * q3.x; l1 += wsh[13] * q3.y; l1 += wsh[14] * q3.z; l1 += wsh[15] * q3.w;
  l2 += wsh[16] * q4.x; l2 += wsh[17] * q4.y; l2 += wsh[18] * q4.z; l2 += wsh[19] * q4.w;
  l2 += wsh[20] * q5.x; l2 += wsh[21] * q5.y; l2 += wsh[22] * q5.z; l2 += wsh[23] * q5.w;
}

// ---------- psi + psi-Gram G + raw bubble Gram BB ----------
__global__ void k_prep(const float* __restrict__ bub, float* __restrict__ ws) {
  __shared__ float braw[Jc * Dc];
  __shared__ float psi[Jc * Dc];
  __shared__ float nrm[Jc];
  int tid = threadIdx.x;
  for (int i = tid; i < Jc * Dc; i += 256) braw[i] = bub[i];
  __syncthreads();
  if (tid < Jc) {
    float s = 0.f;
    for (int d = 0; d < Dc; ++d) { float b = braw[tid * Dc + d]; s += b * b; }
    nrm[tid] = sqrtf(s) + 1e-10f;
  }
  __syncthreads();
  for (int i = tid; i < Jc * Dc; i += 256) {
    float v = braw[i] / nrm[i / Dc];
    psi[i] = v;
    ws[WS_PSI + i] = v;
  }
  __syncthreads();
  for (int i = tid; i < Jc * Jc; i += 256) {
    int r = i / Jc, c = i % Jc;
    float g = 0.f, b = 0.f;
    for (int d = 0; d < Dc; ++d) {
      g += psi[r * Dc + d] * psi[c * Dc + d];
      b += braw[r * Dc + d] * braw[c * Dc + d];
    }
    ws[WS_G + i] = g;
    ws[WS_BB + i] = b;
  }
}

// ---------- per-token precompute: BX[t][j] = bub_j . E[tok_t], XN[t] = |x|^2 ----------
__global__ void k_tok(const int* __restrict__ tok, const float* __restrict__ E,
                      const float* __restrict__ bub, float* __restrict__ ws) {
  int t = blockIdx.x, lane = threadIdx.x;   // 64 threads = 1 wave
  int tk = tok[t];
  float eA = E[(size_t)tk * Dc + lane];
  float eB = E[(size_t)tk * Dc + 64 + lane];
  float xn = wsum64(eA * eA + eB * eB);
  if (lane == 0) ws[WS_XN + t] = xn;
  float p[Jc];
#pragma unroll
  for (int j = 0; j < Jc; ++j)
    p[j] = bub[j * Dc + lane] * eA + bub[j * Dc + 64 + lane] * eB;
#pragma unroll
  for (int j = 0; j < Jc; ++j) p[j] = wsum64(p[j]);
  if (lane == 0) {
#pragma unroll
    for (int j = 0; j < Jc; ++j) ws[WS_BX + (size_t)t * Jc + j] = p[j];
  }
}

// ---------- sequential recurrence, single wave, register-resident ----------
__global__ void k_recur(const int* __restrict__ tok, const float* __restrict__ E,
                        const float* __restrict__ bub, const float* __restrict__ pdb,
                        const float* __restrict__ psn, float* __restrict__ ws) {
  __shared__ float sBX[Tc * Jc];
  __shared__ float sXN[Tc];
  int lane = threadIdx.x;                 // 64 threads = 1 wave
  for (int i = lane; i < Tc * Jc; i += 64) sBX[i] = ws[WS_BX + i];
  if (lane < Tc) sXN[lane] = ws[WS_XN + lane];
  float db = pdb[0];
  float sens = fabsf(psn[0]);
  int tokv = tok[lane];
  float bubA[Jc], bubB[Jc];
#pragma unroll
  for (int j = 0; j < Jc; ++j) {
    bubA[j] = bub[j * Dc + lane];
    bubB[j] = bub[j * Dc + 64 + lane];
  }
  int jme = (lane < Jc) ? lane : (Jc - 1);
  int kme = jme >> 3;
  float BBrow[Jc];
#pragma unroll
  for (int j = 0; j < Jc; ++j) BBrow[j] = ws[WS_BB + (size_t)jme * Jc + j];
  __syncthreads();
  float mmA[Kc] = {0.f, 0.f, 0.f}, mmB[Kc] = {0.f, 0.f, 0.f};
  float BMv[Kc] = {0.f, 0.f, 0.f};
  int tk0 = __shfl(tokv, 0);
  float xA = E[(size_t)tk0 * Dc + lane];
  float xB = E[(size_t)tk0 * Dc + 64 + lane];
  for (int t = 0; t < Tc; ++t) {
    float nxA = 0.f, nxB = 0.f;
    if (t + 1 < Tc) {
      int nk = __shfl(tokv, t + 1);
      nxA = E[(size_t)nk * Dc + lane];
      nxB = E[(size_t)nk * Dc + 64 + lane];
    }
    float dk[Kc], nk2[Kc];
#pragma unroll
    for (int k = 0; k < Kc; ++k) {
      dk[k]  = wsum64(mmA[k] * xA + mmB[k] * xB);
      nk2[k] = wsum64(mmA[k] * mmA[k] + mmB[k] * mmB[k]);
    }
    float xn = sqrtf(sXN[t]) + 1e-10f;
    float dec[Kc], xmA[Kc], xmB[Kc];
#pragma unroll
    for (int k = 0; k < Kc; ++k) {
      float mn = sqrtf(nk2[k]) + 1e-10f;
      float cosv = dk[k] / (xn * mn);
      float nov = (mn > 1e-8f) ? (1.f - cosv) : 1.f;
      dec[k] = 1.f / (1.f + expf(-(db - sens * nov)));
      xmA[k] = xA + dec[k] * mmA[k];
      xmB[k] = xB + dec[k] * mmB[k];
    }
    float bxj = sBX[t * Jc + jme];
    float decS = (kme == 0) ? dec[0] : ((kme == 1) ? dec[1] : dec[2]);
    float sc = (bxj + decS * BMv[kme]) * (DIVW * INV_SQRT_D);
    float mx = sc;
    mx = fmaxf(mx, __shfl_xor(mx, 1));
    mx = fmaxf(mx, __shfl_xor(mx, 2));
    mx = fmaxf(mx, __shfl_xor(mx, 4));
    float e = expf(sc - mx);
    float ss = e;
    ss += __shfl_xor(ss, 1);
    ss += __shfl_xor(ss, 2);
    ss += __shfl_xor(ss, 4);
    float w = e / ss;
    if (lane < Jc) ws[WS_WALL + (size_t)t * Jc + lane] = w;
    float wj[Jc];
#pragma unroll
    for (int j = 0; j < Jc; ++j) wj[j] = __shfl(w, j);
#pragma unroll
    for (int k = 0; k < Kc; ++k) {
      float accA = 0.f, accB = 0.f;
#pragma unroll
      for (int n = 0; n < NBc; ++n) {
        float om = 1.f - wj[k * NBc + n];
        accA += om * bubA[k * NBc + n];
        accB += om * bubB[k * NBc + n];
      }
      float od8 = (1.f - dec[k]) * 0.125f;
      mmA[k] = dec[k] * mmA[k] + od8 * (xmA[k] + accA);
      mmB[k] = dec[k] * mmB[k] + od8 * (xmB[k] + accB);
    }
#pragma unroll
    for (int k = 0; k < Kc; ++k) {
      float bxm = bxj + dec[k] * BMv[k];
      float s2 = 0.f;
#pragma unroll
      for (int n = 0; n < NBc; ++n) s2 += (1.f - wj[k * NBc + n]) * BBrow[k * NBc + n];
      BMv[k] = dec[k] * BMv[k] + (1.f - dec[k]) * 0.125f * (bxm + s2);
    }
    xA = nxA; xB = nxB;
  }
}

// ---------- P2T[v][j] = (E[v] . psi_j)^2  (transposed layout, 96B rows) ----------
__global__ void k_proj(const float* __restrict__ E, float* __restrict__ ws) {
  __shared__ float4 psi4[Jc][Dc / 4];
  int tid = threadIdx.x;
  for (int i = tid; i < Jc * Dc / 4; i += 256)
    ((float4*)psi4)[i] = ((const float4*)(ws + WS_PSI))[i];
  __syncthreads();
  int v = blockIdx.x * 256 + tid;
  if (v >= Vv) return;
  float acc[Jc];
#pragma unroll
  for (int j = 0; j < Jc; ++j) acc[j] = 0.f;
  const float4* e4 = (const float4*)(E + (size_t)v * Dc);
  for (int d = 0; d < Dc / 4; ++d) {
    float4 e = e4[d];
#pragma unroll
    for (int j = 0; j < Jc; ++j) {
      float4 p = psi4[j][d];
      acc[j] += e.x * p.x + e.y * p.y + e.z * p.z + e.w * p.w;
    }
  }
  float* o = ws + WS_P2T + (size_t)v * Jc;
#pragma unroll
  for (int j = 0; j < Jc; ++j) o[j] = acc[j] * acc[j];
}

// ---------- rho[t] = sum_j (w_j/3) psi_j psi_j^T  (one block per t) ----------
__global__ void k_rho(const float* __restrict__ ws, float* __restrict__ out) {
  int t = blockIdx.x;
  __shared__ float psis[Jc * Dc];
  __shared__ float wsh[Jc];
  int tid = threadIdx.x;
  for (int i = tid; i < Jc * Dc; i += 256) psis[i] = ws[WS_PSI + i];
  if (tid < Jc) wsh[tid] = ws[WS_WALL + (size_t)t * Jc + tid] * (1.f / 3.f);
  __syncthreads();
  int d = tid >> 1, eh = (tid & 1) * 64;
  float4 acc[16];
#pragma unroll
  for (int i = 0; i < 16; ++i) acc[i] = make_float4(0.f, 0.f, 0.f, 0.f);
  for (int j = 0; j < Jc; ++j) {
    float a = wsh[j] * psis[j * Dc + d];
    const float4* pr = (const float4*)&psis[j * Dc + eh];
#pragma unroll
    for (int i = 0; i < 16; ++i) {
      float4 p = pr[i];
      acc[i].x += a * p.x; acc[i].y += a * p.y; acc[i].z += a * p.z; acc[i].w += a * p.w;
    }
  }
  float* o = out + OFF_RHO + (size_t)t * Dc * Dc + (size_t)d * Dc + eh;
#pragma unroll
  for (int i = 0; i < 16; ++i) ((float4*)o)[i] = acc[i];
}

// ---------- fused: softmax partials (ch<NCH, NO logit stores) + Jacobi eig (ch==NCH) ----------
__global__ void k_logits_eig(float* __restrict__ ws, float* __restrict__ out) {
  int ch = blockIdx.x, t = blockIdx.y, tid = threadIdx.x;
  __shared__ float wsh[Jc];
  __shared__ float rm[4][4], rs[4][4], rsl2[4];
  __shared__ float A[Jc * 25];         // eig branch; stride 25: bank-decorrelated

  if (ch == NCH) {
    // ----- eig branch: one wave per t, R0-proven LDS Jacobi -----
    if (tid >= 64) return;             // waves 1..3 exit (wave-uniform)
    int lane = tid;
    for (int i = lane; i < Jc * Jc; i += 64) {
      int r = i / Jc, c = i % Jc;
      A[r * 25 + c] = ws[WS_G + i] *
                      sqrtf(ws[WS_WALL + (size_t)t * Jc + r] * ws[WS_WALL + (size_t)t * Jc + c]) *
                      (1.f / 3.f);
    }
    __builtin_amdgcn_wave_barrier();
    for (int sweep = 0; sweep < 7; ++sweep) {
      for (int rr = 0; rr < 23; ++rr) {
        float cv = 1.f, sv = 0.f;
        if (lane < Jc) {
          int j = lane;
          int m = (j == 23) ? rr : ((j == rr) ? 23 : (2 * rr + 23 - j) % 23);
          int lo = min(j, m), hi = max(j, m);
          float ajj = A[j * 25 + j];
          float alh = A[lo * 25 + hi];
          float amm = __shfl(ajj, m);
          float app = (j == lo) ? ajj : amm;
          float aqq = (j == lo) ? amm : ajj;
          if (fabsf(alh) > 1e-20f) {
            float th = (aqq - app) / (2.f * alh);
            float tt = 1.f / (fabsf(th) + sqrtf(1.f + th * th));
            if (th < 0.f) tt = -tt;
            cv = 1.f / sqrtf(1.f + tt * tt);
            sv = tt * cv;
          }
        }
        __builtin_amdgcn_wave_barrier();
#pragma unroll
        for (int it = 0; it < 3; ++it) {
          int b = lane + 64 * it;
          int bb = (b < 144) ? b : 143;
          int pi = bb / 12, pj = bb % 12;
          int p0, q0, p1, q1;
          if (pi == 0) { p0 = rr; q0 = 23; }
          else { int a = (rr + pi) % 23, b2 = (rr + 23 - pi) % 23; p0 = min(a, b2); q0 = max(a, b2); }
          if (pj == 0) { p1 = rr; q1 = 23; }
          else { int a = (rr + pj) % 23, b2 = (rr + 23 - pj) % 23; p1 = min(a, b2); q1 = max(a, b2); }
          float ci = __shfl(cv, p0), si = __shfl(sv, p0);
          float cj = __shfl(cv, p1), sj = __shfl(sv, p1);
          if (b < 144) {
            float m00 = A[p0 * 25 + p1], m01 = A[p0 * 25 + q1];
            float m10 = A[q0 * 25 + p1], m11 = A[q0 * 25 + q1];
            float r00 = ci * m00 - si * m10, r01 = ci * m01 - si * m11;
            float r10 = si * m00 + ci * m10, r11 = si * m01 + ci * m11;
            float o00 = cj * r00 - sj * r01, o01 = sj * r00 + cj * r01;
            float o10 = cj * r10 - sj * r11, o11 = sj * r10 + cj * r11;
            A[p0 * 25 + p1] = o00; A[p0 * 25 + q1] = o01;
            A[q0 * 25 + p1] = o10; A[q0 * 25 + q1] = o11;
          }
        }
        __builtin_amdgcn_wave_barrier();
      }
    }
    float lam = 0.f;
    if (lane < Jc) lam = fmaxf(A[lane * 25 + lane], 1e-12f);
    float tot = lam;
#pragma unroll
    for (int off = 32; off; off >>= 1) tot += __shfl_down(tot, off);
    tot = __shfl(tot, 0);
    tot += (float)(Dc - Jc) * 1e-12f;
    float term = 0.f;
    if (lane < Jc) { float p = lam / tot; term = p * logf(p); }
#pragma unroll
    for (int off = 32; off; off >>= 1) term += __shfl_down(term, off);
    if (lane == 0) {
      float pe = 1e-12f / tot;
      out[OFF_S + t] = -(term + (float)(Dc - Jc) * pe * logf(pe));
    }
    return;
  }

  // ----- partials branch: recompute logits from P2T[v][j], store NOTHING to out -----
  if (tid < Jc) wsh[tid] = ws[WS_WALL + (size_t)t * Jc + tid];
  __syncthreads();
  float m[4] = {-INFINITY, -INFINITY, -INFINITY, -INFINITY};
  float s[4] = {0.f, 0.f, 0.f, 0.f};
  float sl = 0.f;
  const float* p2 = ws + WS_P2T;
  for (int r = 0; r < 4; ++r) {
    int v = ch * CHV + r * 256 + tid;
    if (v >= Vv) break;
    float l0, l1, l2;
    logits_from_row(p2, wsh, v, l0, l1, l2);
    float l[4] = { l0, l1, l2, (l0 + l1 + l2) * (1.f / 3.f) };
#pragma unroll
    for (int d = 0; d < 4; ++d) {
      float li = l[d];
      if (li > m[d]) {
        float e = expf(m[d] - li);
        s[d] = s[d] * e + 1.f;
        if (d == 3) sl = sl * e + li;
        m[d] = li;
      } else {
        float e = expf(li - m[d]);
        s[d] += e;
        if (d == 3) sl += e * li;
      }
    }
  }
#pragma unroll
  for (int off = 32; off; off >>= 1) {
#pragma unroll
    for (int d = 0; d < 3; ++d) {
      float om = __shfl_down(m[d], off);
      float os = __shfl_down(s[d], off);
      comb(m[d], s[d], om, os);
    }
    float om = __shfl_down(m[3], off);
    float os = __shfl_down(s[3], off);
    float osl = __shfl_down(sl, off);
    comb_sl(m[3], s[3], sl, om, os, osl);
  }
  int wv = tid >> 6, ln = tid & 63;
  if (ln == 0) {
#pragma unroll
    for (int d = 0; d < 4; ++d) { rm[wv][d] = m[d]; rs[wv][d] = s[d]; }
    rsl2[wv] = sl;
  }
  __syncthreads();
  if (tid == 0) {
    float* part = ws + WS_PART + ((size_t)t * NCH + ch) * 9;
    for (int d = 0; d < 3; ++d) {
      float M = rm[0][d], S = rs[0][d];
      for (int w2 = 1; w2 < 4; ++w2) comb(M, S, rm[w2][d], rs[w2][d]);
      part[d] = M; part[4 + d] = S;
    }
    float M = rm[0][3], S = rs[0][3], SL = rsl2[0];
    for (int w2 = 1; w2 < 4; ++w2) comb_sl(M, S, SL, rm[w2][3], rs[w2][3], rsl2[w2]);
    part[3] = M; part[7] = S; part[8] = SL;
  }
}

// ---------- merge chunk partials -> logZ[t][4]; H, F ----------
__global__ void k_reduce(float* __restrict__ ws, float* __restrict__ out) {
  int t = blockIdx.x, tid = threadIdx.x;
  if (tid < 4) {
    float M = -INFINITY, S = 0.f, SL = 0.f;
    for (int ch = 0; ch < NCH; ++ch) {
      const float* p = ws + WS_PART + ((size_t)t * NCH + ch) * 9;
      if (tid == 3) comb_sl(M, S, SL, p[3], p[7], p[8]);
      else          comb(M, S, p[tid], p[4 + tid]);
    }
    float lz = M + logf(S);
    ws[WS_LOGZ + (size_t)t * 4 + tid] = lz;
    if (tid == 3) {
      float H = lz - SL / S;
      float Srho = out[OFF_S + t];
      out[OFF_H + t] = H;
      out[OFF_F + t] = H - Srho;
    }
  }
}

// ---------- single norm pass: recompute logits, write all 4 prob streams ----------
__global__ void k_norm2(const float* __restrict__ ws, float* __restrict__ out) {
  int ch = blockIdx.x, t = blockIdx.y, tid = threadIdx.x;
  __shared__ float wsh[Jc];
  __shared__ float lzs[4];
  if (tid < Jc) wsh[tid] = ws[WS_WALL + (size_t)t * Jc + tid];
  if (tid >= 32 && tid < 36) lzs[tid - 32] = ws[WS_LOGZ + (size_t)t * 4 + (tid - 32)];
  __syncthreads();
  const float* p2 = ws + WS_P2T;
  for (int r = 0; r < 4; ++r) {
    int v = ch * CHV + r * 256 + tid;
    if (v >= Vv) break;
    float l0, l1, l2;
    logits_from_row(p2, wsh, v, l0, l1, l2);
    float l3 = (l0 + l1 + l2) * (1.f / 3.f);
    out[OFF_TOK + (size_t)t * Vv + v] = expf(l3 - lzs[3]);
    out[OFF_PF + ((size_t)t * Kc + 0) * Vv + v] = expf(l0 - lzs[0]);
    out[OFF_PF + ((size_t)t * Kc + 1) * Vv + v] = expf(l1 - lzs[1]);
    out[OFF_PF + ((size_t)t * Kc + 2) * Vv + v] = expf(l2 - lzs[2]);
  }
}

extern "C" void kernel_launch(void* const* d_in, const int* in_sizes, int n_in,
                              void* d_out, int out_size, void* d_ws, size_t ws_size,
                              hipStream_t stream) {
  const int*   tokens = (const int*)d_in[0];
  const float* E      = (const float*)d_in[1];
  const float* bub    = (const float*)d_in[2];
  const float* pdb    = (const float*)d_in[3];
  const float* psn    = (const float*)d_in[4];
  float* out = (float*)d_out;
  float* ws  = (float*)d_ws;

  k_prep<<<1, 256, 0, stream>>>(bub, ws);
  k_proj<<<(Vv + 255) / 256, 256, 0, stream>>>(E, ws);
  k_tok<<<Tc, 64, 0, stream>>>(tokens, E, bub, ws);
  k_recur<<<1, 64, 0, stream>>>(tokens, E, bub, pdb, psn, ws);
  k_rho<<<Tc, 256, 0, stream>>>(ws, out);
  k_logits_eig<<<dim3(NCH + 1, Tc), 256, 0, stream>>>(ws, out);
  k_reduce<<<Tc, 64, 0, stream>>>(ws, out);
  k_norm2<<<dim3(NCH, Tc), 256, 0, stream>>>(ws, out);
}

// Round 8
// 445.107 us; speedup vs baseline: 1.1277x; 1.1277x over previous
//
#include <hip/hip_runtime.h>
#include <math.h>

namespace {
constexpr int Vv  = 50257;
constexpr int Dc  = 128;
constexpr int Kc  = 3;
constexpr int NBc = 8;
constexpr int Jc  = 24;      // K*NB
constexpr int Tc  = 64;
constexpr int CHV = 1024;                      // vocab elems per block chunk
constexpr int NCH = (Vv + CHV - 1) / CHV;      // 50
constexpr float INV_SQRT_D = 0.08838834764831845f;
constexpr float DIVW = 2.0f;

// ws layout (float offsets)
constexpr size_t WS_PSI  = 0;        // 24*128
constexpr size_t WS_G    = 4096;     // 24*24 (psi gram)
constexpr size_t WS_BB   = 5120;     // 24*24 (raw bubble gram)
constexpr size_t WS_XN   = 6144;     // 64   |x_t|^2
constexpr size_t WS_BX   = 6400;     // 64*24 bub_j . x_t
constexpr size_t WS_WALL = 8192;     // 64*24
constexpr size_t WS_PART = 12288;    // 64*50*9 = 28800
constexpr size_t WS_LOGZ = 45056;    // 64*4
constexpr size_t WS_P2T  = 65536;    // V*24, layout [v][j]: row = 96B, 16B-aligned

// out layout (float offsets), reference return order
constexpr size_t OFF_TOK = 0;
constexpr size_t OFF_RHO = (size_t)Tc * Vv;
constexpr size_t OFF_S   = OFF_RHO + (size_t)Tc * Dc * Dc;
constexpr size_t OFF_H   = OFF_S + Tc;
constexpr size_t OFF_F   = OFF_H + Tc;
constexpr size_t OFF_PF  = OFF_F + Tc;
}

__device__ __forceinline__ float wsum64(float v) {
#pragma unroll
  for (int m = 1; m < 64; m <<= 1) v += __shfl_xor(v, m);
  return v;
}

// online-softmax merge helpers
__device__ __forceinline__ void comb(float& m1, float& s1, float m2, float s2) {
  float M = fmaxf(m1, m2);
  float e1 = (s1 > 0.f) ? expf(m1 - M) : 0.f;
  float e2 = (s2 > 0.f) ? expf(m2 - M) : 0.f;
  s1 = s1 * e1 + s2 * e2;
  m1 = M;
}
__device__ __forceinline__ void comb_sl(float& m1, float& s1, float& sl1,
                                        float m2, float s2, float sl2) {
  float M = fmaxf(m1, m2);
  float e1 = (s1 > 0.f) ? expf(m1 - M) : 0.f;
  float e2 = (s2 > 0.f) ? expf(m2 - M) : 0.f;
  s1 = s1 * e1 + s2 * e2;
  sl1 = sl1 * e1 + sl2 * e2;
  m1 = M;
}

// shared logit recompute: 6 float4 loads + sequential FMA chains (identical
// op order in pass1 and pass2 so both passes produce identical l-values)
__device__ __forceinline__ void logits_from_row(const float* __restrict__ p2,
                                                const float* __restrict__ wsh,
                                                int v, float& l0, float& l1, float& l2) {
  const float4* row = (const float4*)(p2 + (size_t)v * Jc);
  float4 q0 = row[0], q1 = row[1], q2 = row[2], q3 = row[3], q4 = row[4], q5 = row[5];
  l0 = 0.f; l1 = 0.f; l2 = 0.f;
  l0 += wsh[0]  * q0.x; l0 += wsh[1]  * q0.y; l0 += wsh[2]  * q0.z; l0 += wsh[3]  * q0.w;
  l0 += wsh[4]  * q1.x; l0 += wsh[5]  * q1.y; l0 += wsh[6]  * q1.z; l0 += wsh[7]  * q1.w;
  l1 += wsh[8]  * q2.x; l1 += wsh[9]  * q2.y; l1 += wsh[10] * q2.z; l1 += wsh[11] * q2.w;
  l1 += wsh[12] * q3.x; l1 += wsh[13] * q3.y; l1 += wsh[14] * q3.z; l1 += wsh[15] * q3.w;
  l2 += wsh[16] * q4.x; l2 += wsh[17] * q4.y; l2 += wsh[18] * q4.z; l2 += wsh[19] * q4.w;
  l2 += wsh[20] * q5.x; l2 += wsh[21] * q5.y; l2 += wsh[22] * q5.z; l2 += wsh[23] * q5.w;
}

// ---------- psi + psi-Gram G + raw bubble Gram BB ----------
__global__ void k_prep(const float* __restrict__ bub, float* __restrict__ ws) {
  __shared__ float braw[Jc * Dc];
  __shared__ float psi[Jc * Dc];
  __shared__ float nrm[Jc];
  int tid = threadIdx.x;
  for (int i = tid; i < Jc * Dc; i += 256) braw[i] = bub[i];
  __syncthreads();
  if (tid < Jc) {
    float s = 0.f;
    for (int d = 0; d < Dc; ++d) { float b = braw[tid * Dc + d]; s += b * b; }
    nrm[tid] = sqrtf(s) + 1e-10f;
  }
  __syncthreads();
  for (int i = tid; i < Jc * Dc; i += 256) {
    float v = braw[i] / nrm[i / Dc];
    psi[i] = v;
    ws[WS_PSI + i] = v;
  }
  __syncthreads();
  for (int i = tid; i < Jc * Jc; i += 256) {
    int r = i / Jc, c = i % Jc;
    float g = 0.f, b = 0.f;
    for (int d = 0; d < Dc; ++d) {
      g += psi[r * Dc + d] * psi[c * Dc + d];
      b += braw[r * Dc + d] * braw[c * Dc + d];
    }
    ws[WS_G + i] = g;
    ws[WS_BB + i] = b;
  }
}

// ---------- fused: per-token BX/XN (first 64 blocks) + P2T (rest) ----------
__global__ void k_projtok(const int* __restrict__ tok, const float* __restrict__ E,
                          const float* __restrict__ bub, float* __restrict__ ws) {
  __shared__ float4 psi4[Jc][Dc / 4];
  int bid = blockIdx.x, tid = threadIdx.x;
  if (bid < Tc) {
    // tok branch: one wave
    if (tid >= 64) return;
    int t = bid, lane = tid;
    int tk = tok[t];
    float eA = E[(size_t)tk * Dc + lane];
    float eB = E[(size_t)tk * Dc + 64 + lane];
    float xn = wsum64(eA * eA + eB * eB);
    if (lane == 0) ws[WS_XN + t] = xn;
    float p[Jc];
#pragma unroll
    for (int j = 0; j < Jc; ++j)
      p[j] = bub[j * Dc + lane] * eA + bub[j * Dc + 64 + lane] * eB;
#pragma unroll
    for (int j = 0; j < Jc; ++j) p[j] = wsum64(p[j]);
    if (lane == 0) {
#pragma unroll
      for (int j = 0; j < Jc; ++j) ws[WS_BX + (size_t)t * Jc + j] = p[j];
    }
    return;
  }
  // proj branch: P2T[v][j] = (E[v].psi_j)^2, transposed 96B rows
  for (int i = tid; i < Jc * Dc / 4; i += 256)
    ((float4*)psi4)[i] = ((const float4*)(ws + WS_PSI))[i];
  __syncthreads();
  int v = (bid - Tc) * 256 + tid;
  if (v >= Vv) return;
  float acc[Jc];
#pragma unroll
  for (int j = 0; j < Jc; ++j) acc[j] = 0.f;
  const float4* e4 = (const float4*)(E + (size_t)v * Dc);
  for (int d = 0; d < Dc / 4; ++d) {
    float4 e = e4[d];
#pragma unroll
    for (int j = 0; j < Jc; ++j) {
      float4 p = psi4[j][d];
      acc[j] += e.x * p.x + e.y * p.y + e.z * p.z + e.w * p.w;
    }
  }
  float* o = ws + WS_P2T + (size_t)v * Jc;
#pragma unroll
  for (int j = 0; j < Jc; ++j) o[j] = acc[j] * acc[j];
}

// ---------- sequential recurrence, single wave, register-resident ----------
__global__ void k_recur(const int* __restrict__ tok, const float* __restrict__ E,
                        const float* __restrict__ bub, const float* __restrict__ pdb,
                        const float* __restrict__ psn, float* __restrict__ ws) {
  __shared__ float sBX[Tc * Jc];
  __shared__ float sXN[Tc];
  int lane = threadIdx.x;                 // 64 threads = 1 wave
  for (int i = lane; i < Tc * Jc; i += 64) sBX[i] = ws[WS_BX + i];
  if (lane < Tc) sXN[lane] = ws[WS_XN + lane];
  float db = pdb[0];
  float sens = fabsf(psn[0]);
  int tokv = tok[lane];
  float bubA[Jc], bubB[Jc];
#pragma unroll
  for (int j = 0; j < Jc; ++j) {
    bubA[j] = bub[j * Dc + lane];
    bubB[j] = bub[j * Dc + 64 + lane];
  }
  int jme = (lane < Jc) ? lane : (Jc - 1);
  int kme = jme >> 3;
  float BBrow[Jc];
#pragma unroll
  for (int j = 0; j < Jc; ++j) BBrow[j] = ws[WS_BB + (size_t)jme * Jc + j];
  __syncthreads();
  float mmA[Kc] = {0.f, 0.f, 0.f}, mmB[Kc] = {0.f, 0.f, 0.f};
  float BMv[Kc] = {0.f, 0.f, 0.f};
  int tk0 = __shfl(tokv, 0);
  float xA = E[(size_t)tk0 * Dc + lane];
  float xB = E[(size_t)tk0 * Dc + 64 + lane];
  for (int t = 0; t < Tc; ++t) {
    float nxA = 0.f, nxB = 0.f;
    if (t + 1 < Tc) {
      int nk = __shfl(tokv, t + 1);
      nxA = E[(size_t)nk * Dc + lane];
      nxB = E[(size_t)nk * Dc + 64 + lane];
    }
    float dk[Kc], nk2[Kc];
#pragma unroll
    for (int k = 0; k < Kc; ++k) {
      dk[k]  = wsum64(mmA[k] * xA + mmB[k] * xB);
      nk2[k] = wsum64(mmA[k] * mmA[k] + mmB[k] * mmB[k]);
    }
    float xn = sqrtf(sXN[t]) + 1e-10f;
    float dec[Kc], xmA[Kc], xmB[Kc];
#pragma unroll
    for (int k = 0; k < Kc; ++k) {
      float mn = sqrtf(nk2[k]) + 1e-10f;
      float cosv = dk[k] / (xn * mn);
      float nov = (mn > 1e-8f) ? (1.f - cosv) : 1.f;
      dec[k] = 1.f / (1.f + expf(-(db - sens * nov)));
      xmA[k] = xA + dec[k] * mmA[k];
      xmB[k] = xB + dec[k] * mmB[k];
    }
    float bxj = sBX[t * Jc + jme];
    float decS = (kme == 0) ? dec[0] : ((kme == 1) ? dec[1] : dec[2]);
    float sc = (bxj + decS * BMv[kme]) * (DIVW * INV_SQRT_D);
    float mx = sc;
    mx = fmaxf(mx, __shfl_xor(mx, 1));
    mx = fmaxf(mx, __shfl_xor(mx, 2));
    mx = fmaxf(mx, __shfl_xor(mx, 4));
    float e = expf(sc - mx);
    float ss = e;
    ss += __shfl_xor(ss, 1);
    ss += __shfl_xor(ss, 2);
    ss += __shfl_xor(ss, 4);
    float w = e / ss;
    if (lane < Jc) ws[WS_WALL + (size_t)t * Jc + lane] = w;
    float wj[Jc];
#pragma unroll
    for (int j = 0; j < Jc; ++j) wj[j] = __shfl(w, j);
#pragma unroll
    for (int k = 0; k < Kc; ++k) {
      float accA = 0.f, accB = 0.f;
#pragma unroll
      for (int n = 0; n < NBc; ++n) {
        float om = 1.f - wj[k * NBc + n];
        accA += om * bubA[k * NBc + n];
        accB += om * bubB[k * NBc + n];
      }
      float od8 = (1.f - dec[k]) * 0.125f;
      mmA[k] = dec[k] * mmA[k] + od8 * (xmA[k] + accA);
      mmB[k] = dec[k] * mmB[k] + od8 * (xmB[k] + accB);
    }
#pragma unroll
    for (int k = 0; k < Kc; ++k) {
      float bxm = bxj + dec[k] * BMv[k];
      float s2 = 0.f;
#pragma unroll
      for (int n = 0; n < NBc; ++n) s2 += (1.f - wj[k * NBc + n]) * BBrow[k * NBc + n];
      BMv[k] = dec[k] * BMv[k] + (1.f - dec[k]) * 0.125f * (bxm + s2);
    }
    xA = nxA; xB = nxB;
  }
}

// ---------- fused main: [0,64) eig | [64,128) rho | [128,..) softmax partials ----------
// eig blocks FIRST in dispatch order so their 146us latency chain starts at
// t=0 of the dispatch; rho + partials fill the remaining CUs underneath.
__global__ void k_main(float* __restrict__ ws, float* __restrict__ out) {
  __shared__ float sh[Jc * Dc];        // rho: psis (12KB); eig: A (600 floats used)
  __shared__ float wsh[Jc];
  __shared__ float rm[4][4], rs[4][4], rsl2[4];
  int bid = blockIdx.x, tid = threadIdx.x;

  if (bid < Tc) {
    // ----- eig branch: one wave per t, R0-proven LDS Jacobi -----
    if (tid >= 64) return;
    int t = bid, lane = tid;
    float* A = sh;                     // stride 25: bank-decorrelated
    for (int i = lane; i < Jc * Jc; i += 64) {
      int r = i / Jc, c = i % Jc;
      A[r * 25 + c] = ws[WS_G + i] *
                      sqrtf(ws[WS_WALL + (size_t)t * Jc + r] * ws[WS_WALL + (size_t)t * Jc + c]) *
                      (1.f / 3.f);
    }
    __builtin_amdgcn_wave_barrier();
    for (int sweep = 0; sweep < 7; ++sweep) {
      for (int rr = 0; rr < 23; ++rr) {
        float cv = 1.f, sv = 0.f;
        if (lane < Jc) {
          int j = lane;
          int m = (j == 23) ? rr : ((j == rr) ? 23 : (2 * rr + 23 - j) % 23);
          int lo = min(j, m), hi = max(j, m);
          float ajj = A[j * 25 + j];
          float alh = A[lo * 25 + hi];
          float amm = __shfl(ajj, m);
          float app = (j == lo) ? ajj : amm;
          float aqq = (j == lo) ? amm : ajj;
          if (fabsf(alh) > 1e-20f) {
            float th = (aqq - app) / (2.f * alh);
            float tt = 1.f / (fabsf(th) + sqrtf(1.f + th * th));
            if (th < 0.f) tt = -tt;
            cv = 1.f / sqrtf(1.f + tt * tt);
            sv = tt * cv;
          }
        }
        __builtin_amdgcn_wave_barrier();
#pragma unroll
        for (int it = 0; it < 3; ++it) {
          int b = lane + 64 * it;
          int bb = (b < 144) ? b : 143;
          int pi = bb / 12, pj = bb % 12;
          int p0, q0, p1, q1;
          if (pi == 0) { p0 = rr; q0 = 23; }
          else { int a = (rr + pi) % 23, b2 = (rr + 23 - pi) % 23; p0 = min(a, b2); q0 = max(a, b2); }
          if (pj == 0) { p1 = rr; q1 = 23; }
          else { int a = (rr + pj) % 23, b2 = (rr + 23 - pj) % 23; p1 = min(a, b2); q1 = max(a, b2); }
          float ci = __shfl(cv, p0), si = __shfl(sv, p0);
          float cj = __shfl(cv, p1), sj = __shfl(sv, p1);
          if (b < 144) {
            float m00 = A[p0 * 25 + p1], m01 = A[p0 * 25 + q1];
            float m10 = A[q0 * 25 + p1], m11 = A[q0 * 25 + q1];
            float r00 = ci * m00 - si * m10, r01 = ci * m01 - si * m11;
            float r10 = si * m00 + ci * m10, r11 = si * m01 + ci * m11;
            float o00 = cj * r00 - sj * r01, o01 = sj * r00 + cj * r01;
            float o10 = cj * r10 - sj * r11, o11 = sj * r10 + cj * r11;
            A[p0 * 25 + p1] = o00; A[p0 * 25 + q1] = o01;
            A[q0 * 25 + p1] = o10; A[q0 * 25 + q1] = o11;
          }
        }
        __builtin_amdgcn_wave_barrier();
      }
    }
    float lam = 0.f;
    if (lane < Jc) lam = fmaxf(A[lane * 25 + lane], 1e-12f);
    float tot = lam;
#pragma unroll
    for (int off = 32; off; off >>= 1) tot += __shfl_down(tot, off);
    tot = __shfl(tot, 0);
    tot += (float)(Dc - Jc) * 1e-12f;
    float term = 0.f;
    if (lane < Jc) { float p = lam / tot; term = p * logf(p); }
#pragma unroll
    for (int off = 32; off; off >>= 1) term += __shfl_down(term, off);
    if (lane == 0) {
      float pe = 1e-12f / tot;
      out[OFF_S + t] = -(term + (float)(Dc - Jc) * pe * logf(pe));
    }
    return;
  }

  if (bid < 2 * Tc) {
    // ----- rho branch: rho[t] = sum_j (w_j/3) psi_j psi_j^T -----
    int t = bid - Tc;
    float* psis = sh;
    for (int i = tid; i < Jc * Dc; i += 256) psis[i] = ws[WS_PSI + i];
    if (tid < Jc) wsh[tid] = ws[WS_WALL + (size_t)t * Jc + tid] * (1.f / 3.f);
    __syncthreads();
    int d = tid >> 1, eh = (tid & 1) * 64;
    float4 acc[16];
#pragma unroll
    for (int i = 0; i < 16; ++i) acc[i] = make_float4(0.f, 0.f, 0.f, 0.f);
    for (int j = 0; j < Jc; ++j) {
      float a = wsh[j] * psis[j * Dc + d];
      const float4* pr = (const float4*)&psis[j * Dc + eh];
#pragma unroll
      for (int i = 0; i < 16; ++i) {
        float4 p = pr[i];
        acc[i].x += a * p.x; acc[i].y += a * p.y; acc[i].z += a * p.z; acc[i].w += a * p.w;
      }
    }
    float* o = out + OFF_RHO + (size_t)t * Dc * Dc + (size_t)d * Dc + eh;
#pragma unroll
    for (int i = 0; i < 16; ++i) ((float4*)o)[i] = acc[i];
    return;
  }

  // ----- partials branch: recompute logits from P2T[v][j], online softmax -----
  int lin = bid - 2 * Tc;
  int t = lin / NCH, ch = lin % NCH;
  if (tid < Jc) wsh[tid] = ws[WS_WALL + (size_t)t * Jc + tid];
  __syncthreads();
  float m[4] = {-INFINITY, -INFINITY, -INFINITY, -INFINITY};
  float s[4] = {0.f, 0.f, 0.f, 0.f};
  float sl = 0.f;
  const float* p2 = ws + WS_P2T;
  for (int r = 0; r < 4; ++r) {
    int v = ch * CHV + r * 256 + tid;
    if (v >= Vv) break;
    float l0, l1, l2;
    logits_from_row(p2, wsh, v, l0, l1, l2);
    float l[4] = { l0, l1, l2, (l0 + l1 + l2) * (1.f / 3.f) };
#pragma unroll
    for (int d = 0; d < 4; ++d) {
      float li = l[d];
      if (li > m[d]) {
        float e = expf(m[d] - li);
        s[d] = s[d] * e + 1.f;
        if (d == 3) sl = sl * e + li;
        m[d] = li;
      } else {
        float e = expf(li - m[d]);
        s[d] += e;
        if (d == 3) sl += e * li;
      }
    }
  }
#pragma unroll
  for (int off = 32; off; off >>= 1) {
#pragma unroll
    for (int d = 0; d < 3; ++d) {
      float om = __shfl_down(m[d], off);
      float os = __shfl_down(s[d], off);
      comb(m[d], s[d], om, os);
    }
    float om = __shfl_down(m[3], off);
    float os = __shfl_down(s[3], off);
    float osl = __shfl_down(sl, off);
    comb_sl(m[3], s[3], sl, om, os, osl);
  }
  int wv = tid >> 6, ln = tid & 63;
  if (ln == 0) {
#pragma unroll
    for (int d = 0; d < 4; ++d) { rm[wv][d] = m[d]; rs[wv][d] = s[d]; }
    rsl2[wv] = sl;
  }
  __syncthreads();
  if (tid == 0) {
    float* part = ws + WS_PART + ((size_t)t * NCH + ch) * 9;
    for (int d = 0; d < 3; ++d) {
      float M = rm[0][d], S = rs[0][d];
      for (int w2 = 1; w2 < 4; ++w2) comb(M, S, rm[w2][d], rs[w2][d]);
      part[d] = M; part[4 + d] = S;
    }
    float M = rm[0][3], S = rs[0][3], SL = rsl2[0];
    for (int w2 = 1; w2 < 4; ++w2) comb_sl(M, S, SL, rm[w2][3], rs[w2][3], rsl2[w2]);
    part[3] = M; part[7] = S; part[8] = SL;
  }
}

// ---------- merge chunk partials -> logZ[t][4]; H, F ----------
__global__ void k_reduce(float* __restrict__ ws, float* __restrict__ out) {
  int t = blockIdx.x, tid = threadIdx.x;
  if (tid < 4) {
    float M = -INFINITY, S = 0.f, SL = 0.f;
    for (int ch = 0; ch < NCH; ++ch) {
      const float* p = ws + WS_PART + ((size_t)t * NCH + ch) * 9;
      if (tid == 3) comb_sl(M, S, SL, p[3], p[7], p[8]);
      else          comb(M, S, p[tid], p[4 + tid]);
    }
    float lz = M + logf(S);
    ws[WS_LOGZ + (size_t)t * 4 + tid] = lz;
    if (tid == 3) {
      float H = lz - SL / S;
      float Srho = out[OFF_S + t];
      out[OFF_H + t] = H;
      out[OFF_F + t] = H - Srho;
    }
  }
}

// ---------- single norm pass: recompute logits, write all 4 prob streams ----------
__global__ void k_norm2(const float* __restrict__ ws, float* __restrict__ out) {
  int ch = blockIdx.x, t = blockIdx.y, tid = threadIdx.x;
  __shared__ float wsh[Jc];
  __shared__ float lzs[4];
  if (tid < Jc) wsh[tid] = ws[WS_WALL + (size_t)t * Jc + tid];
  if (tid >= 32 && tid < 36) lzs[tid - 32] = ws[WS_LOGZ + (size_t)t * 4 + (tid - 32)];
  __syncthreads();
  const float* p2 = ws + WS_P2T;
  for (int r = 0; r < 4; ++r) {
    int v = ch * CHV + r * 256 + tid;
    if (v >= Vv) break;
    float l0, l1, l2;
    logits_from_row(p2, wsh, v, l0, l1, l2);
    float l3 = (l0 + l1 + l2) * (1.f / 3.f);
    out[OFF_TOK + (size_t)t * Vv + v] = expf(l3 - lzs[3]);
    out[OFF_PF + ((size_t)t * Kc + 0) * Vv + v] = expf(l0 - lzs[0]);
    out[OFF_PF + ((size_t)t * Kc + 1) * Vv + v] = expf(l1 - lzs[1]);
    out[OFF_PF + ((size_t)t * Kc + 2) * Vv + v] = expf(l2 - lzs[2]);
  }
}

extern "C" void kernel_launch(void* const* d_in, const int* in_sizes, int n_in,
                              void* d_out, int out_size, void* d_ws, size_t ws_size,
                              hipStream_t stream) {
  const int*   tokens = (const int*)d_in[0];
  const float* E      = (const float*)d_in[1];
  const float* bub    = (const float*)d_in[2];
  const float* pdb    = (const float*)d_in[3];
  const float* psn    = (const float*)d_in[4];
  float* out = (float*)d_out;
  float* ws  = (float*)d_ws;

  k_prep<<<1, 256, 0, stream>>>(bub, ws);
  k_projtok<<<Tc + (Vv + 255) / 256, 256, 0, stream>>>(tokens, E, bub, ws);
  k_recur<<<1, 64, 0, stream>>>(tokens, E, bub, pdb, psn, ws);
  k_main<<<2 * Tc + Tc * NCH, 256, 0, stream>>>(ws, out);
  k_reduce<<<Tc, 64, 0, stream>>>(ws, out);
  k_norm2<<<dim3(NCH, Tc), 256, 0, stream>>>(ws, out);
}